// Round 1
// baseline (1095.079 us; speedup 1.0000x reference)
//
#include <hip/hip_runtime.h>
#include <math.h>

#define DH 128

// ---------- CSR construction ----------
__global__ void k_deg(const int* __restrict__ col, int* __restrict__ deg, int E) {
    int i = blockIdx.x * blockDim.x + threadIdx.x;
    if (i < E) atomicAdd(&deg[col[i]], 1);
}

__global__ void k_dinv(const int* __restrict__ deg, float* __restrict__ dinv, int N) {
    int i = blockIdx.x * blockDim.x + threadIdx.x;
    if (i < N) dinv[i] = rsqrtf((float)(deg[i] + 1));  // +1 = self loop
}

// single-block exclusive scan over N=100000 degrees
__global__ __launch_bounds__(1024) void k_scan(const int* __restrict__ deg,
                                               int* __restrict__ off, int n) {
    __shared__ int sums[1024];
    int t = threadIdx.x;
    int chunk = (n + 1023) / 1024;
    int s0 = t * chunk;
    int s1 = min(s0 + chunk, n);
    int s = 0;
    for (int i = s0; i < s1; i++) s += deg[i];
    sums[t] = s;
    __syncthreads();
    for (int d = 1; d < 1024; d <<= 1) {
        int v = (t >= d) ? sums[t - d] : 0;
        __syncthreads();
        sums[t] += v;
        __syncthreads();
    }
    int run = (t == 0) ? 0 : sums[t - 1];
    for (int i = s0; i < s1; i++) { off[i] = run; run += deg[i]; }
    if (t == 1023) off[n] = run;
}

__global__ void k_fill(const int* __restrict__ row, const int* __restrict__ col,
                       const int* __restrict__ off, int* __restrict__ cur,
                       int* __restrict__ csr, int E) {
    int i = blockIdx.x * blockDim.x + threadIdx.x;
    if (i < E) {
        int c = col[i];
        int p = atomicAdd(&cur[c], 1);
        csr[off[c] + p] = row[i];
    }
}

// ---------- GEMM: Y[r][c] = (sum_k X[r][k]*W[k][c]) * dinv[r] ----------
// 32 rows per block, W (64KB) + X tile (16KB) staged in LDS.
__global__ __launch_bounds__(256) void k_gemm128(const float* __restrict__ X,
                                                 const float* __restrict__ W,
                                                 const float* __restrict__ dinv,
                                                 float* __restrict__ Y, int nrows) {
    __shared__ float Ws[DH * DH];
    __shared__ float Xs[32 * DH];
    int t = threadIdx.x;
    for (int i = t; i < DH * DH; i += 256) Ws[i] = W[i];
    int row0 = blockIdx.x * 32;
    for (int i = t; i < 32 * DH; i += 256) {
        int r = row0 + (i >> 7);
        Xs[i] = (r < nrows) ? X[r * DH + (i & 127)] : 0.f;
    }
    __syncthreads();
    int c = t & 127;
    int half = t >> 7;  // 0 or 1
    float acc[16];
#pragma unroll
    for (int i = 0; i < 16; i++) acc[i] = 0.f;
    for (int k = 0; k < DH; k++) {
        float w = Ws[k * DH + c];                 // conflict-free (consecutive banks)
#pragma unroll
        for (int i = 0; i < 16; i++)
            acc[i] += Xs[(half + 2 * i) * DH + k] * w;  // broadcast within wave
    }
#pragma unroll
    for (int i = 0; i < 16; i++) {
        int r = row0 + half + 2 * i;
        if (r < nrows) Y[r * DH + c] = acc[i] * dinv[r];
    }
}

// ---------- Aggregation: out[n] = dinv[n]*(sum_{src in CSR[n]} Hs[src] + Hs[n]) + b ----------
// Hs rows are pre-scaled by dinv[row] in the GEMM epilogue.
__global__ void k_agg(const float* __restrict__ Hs, float* __restrict__ O,
                      const float* __restrict__ dinv, const int* __restrict__ off,
                      const int* __restrict__ csr, const float* __restrict__ bias,
                      int elu) {
    int n = blockIdx.x;
    int c = threadIdx.x;  // 128
    int s = off[n], e = off[n + 1];
    float acc = Hs[n * DH + c];  // self loop (already dinv[n]-scaled)
    for (int i = s; i < e; i++) {
        int src = csr[i];
        acc += Hs[src * DH + c];  // coalesced 512B row gather
    }
    float v = acc * dinv[n] + bias[c];
    if (elu) v = v > 0.f ? v : expm1f(v);
    O[n * DH + c] = v;
}

// ---------- Mean pool (batch is sorted) ----------
__global__ void k_pool(const float* __restrict__ H, const int* __restrict__ batch,
                       float* __restrict__ Gsum, int* __restrict__ cnts, int N) {
    int g = blockIdx.x;
    int p = blockIdx.y;
    int c = threadIdx.x;  // 128
    int lo = 0, hi = N;
    while (lo < hi) { int m = (lo + hi) >> 1; if (batch[m] < g) lo = m + 1; else hi = m; }
    int s = lo;
    hi = N;
    while (lo < hi) { int m = (lo + hi) >> 1; if (batch[m] < g + 1) lo = m + 1; else hi = m; }
    int e = lo;
    int len = e - s;
    int parts = (int)gridDim.y;
    int chunk = (len + parts - 1) / parts;
    int i0 = s + p * chunk;
    int i1 = min(i0 + chunk, e);
    float acc = 0.f;
    for (int i = i0; i < i1; i++) acc += H[i * DH + c];
    atomicAdd(&Gsum[g * DH + c], acc);
    if (p == 0 && c == 0) cnts[g] = len;
}

// ---------- MLP head + log_softmax ----------
__global__ __launch_bounds__(64) void k_head(const float* __restrict__ Gsum,
                                             const int* __restrict__ cnts,
                                             const float* __restrict__ W1,
                                             const float* __restrict__ b1,
                                             const float* __restrict__ W2,
                                             const float* __restrict__ b2,
                                             float* __restrict__ out) {
    int g = blockIdx.x;
    int t = threadIdx.x;
    __shared__ float gv[DH];
    __shared__ float mid[20];
    __shared__ float o[10];
    float inv = 1.f / fmaxf((float)cnts[g], 1.f);
    for (int i = t; i < DH; i += 64) gv[i] = Gsum[g * DH + i] * inv;
    __syncthreads();
    if (t < 20) {
        float a = b1[t];
        for (int k = 0; k < DH; k++) a += gv[k] * W1[k * 20 + t];
        mid[t] = fmaxf(a, 0.f);
    }
    __syncthreads();
    if (t < 10) {
        float a = b2[t];
        for (int k = 0; k < 20; k++) a += mid[k] * W2[k * 10 + t];
        o[t] = a;
    }
    __syncthreads();
    if (t == 0) {
        float m = -1e30f;
        for (int j = 0; j < 10; j++) m = fmaxf(m, o[j]);
        float ssum = 0.f;
        for (int j = 0; j < 10; j++) ssum += expf(o[j] - m);
        float l = logf(ssum);
        for (int j = 0; j < 10; j++) out[g * 10 + j] = o[j] - m - l;
    }
}

extern "C" void kernel_launch(void* const* d_in, const int* in_sizes, int n_in,
                              void* d_out, int out_size, void* d_ws, size_t ws_size,
                              hipStream_t stream) {
    const float* x    = (const float*)d_in[0];
    const int*   ei   = (const int*)d_in[1];
    const int*   batch= (const int*)d_in[2];
    const float* W1   = (const float*)d_in[3];
    const float* b1   = (const float*)d_in[4];
    const float* W2   = (const float*)d_in[5];
    const float* b2   = (const float*)d_in[6];
    const float* fc1W = (const float*)d_in[7];
    const float* fc1b = (const float*)d_in[8];
    const float* fc2W = (const float*)d_in[9];
    const float* fc2b = (const float*)d_in[10];
    float* out = (float*)d_out;

    int N = in_sizes[0] / DH;     // 100000
    int E = in_sizes[1] / 2;      // 1600000
    int G = out_size / 10;        // 64

    char* p = (char*)d_ws;
    auto alloc = [&](size_t bytes) {
        char* r = p;
        p += (bytes + 255) & ~(size_t)255;
        return r;
    };
    float* hA   = (float*)alloc((size_t)N * DH * 4);
    float* hB   = (float*)alloc((size_t)N * DH * 4);
    int*   csr  = (int*)alloc((size_t)E * 4);
    int*   deg  = (int*)alloc((size_t)N * 4);
    int*   off  = (int*)alloc((size_t)(N + 1) * 4);
    int*   cur  = (int*)alloc((size_t)N * 4);
    float* dinv = (float*)alloc((size_t)N * 4);
    float* Gsum = (float*)alloc((size_t)G * DH * 4);
    int*   cnts = (int*)alloc((size_t)G * 4);

    const int* row = ei;       // message source
    const int* col = ei + E;   // aggregation target

    hipMemsetAsync(deg, 0, (size_t)N * 4, stream);
    hipMemsetAsync(cur, 0, (size_t)N * 4, stream);
    hipMemsetAsync(Gsum, 0, (size_t)G * DH * 4, stream);

    const int tb = 256;
    k_deg<<<(E + tb - 1) / tb, tb, 0, stream>>>(col, deg, E);
    k_dinv<<<(N + tb - 1) / tb, tb, 0, stream>>>(deg, dinv, N);
    k_scan<<<1, 1024, 0, stream>>>(deg, off, N);
    k_fill<<<(E + tb - 1) / tb, tb, 0, stream>>>(row, col, off, cur, csr, E);

    k_gemm128<<<(N + 31) / 32, 256, 0, stream>>>(x, W1, dinv, hA, N);
    k_agg<<<N, DH, 0, stream>>>(hA, hB, dinv, off, csr, b1, 1);
    k_gemm128<<<(N + 31) / 32, 256, 0, stream>>>(hB, W2, dinv, hA, N);
    k_agg<<<N, DH, 0, stream>>>(hA, hB, dinv, off, csr, b2, 0);

    dim3 pg(G, 8);
    k_pool<<<pg, DH, 0, stream>>>(hB, batch, Gsum, cnts, N);
    k_head<<<G, 64, 0, stream>>>(Gsum, cnts, fc1W, fc1b, fc2W, fc2b, out);
}

// Round 2
// 575.136 us; speedup vs baseline: 1.9040x; 1.9040x over previous
//
#include <hip/hip_runtime.h>
#include <math.h>

#define DH 128

typedef __bf16 bf8_t __attribute__((ext_vector_type(8)));
typedef short short8 __attribute__((ext_vector_type(8)));
typedef float f4_t __attribute__((ext_vector_type(4)));

__device__ inline unsigned short f2b(float f) {
    unsigned int u = __builtin_bit_cast(unsigned int, f);
    u = u + 0x7fffu + ((u >> 16) & 1u);  // RNE
    return (unsigned short)(u >> 16);
}
__device__ inline float b2f(unsigned short h) {
    return __builtin_bit_cast(float, (unsigned int)h << 16);
}

// ---------- CSR construction ----------
__global__ void k_deg(const int* __restrict__ col, int* __restrict__ deg, int E) {
    int i = blockIdx.x * blockDim.x + threadIdx.x;
    if (i < E) atomicAdd(&deg[col[i]], 1);
}

__global__ void k_dinv(const int* __restrict__ deg, float* __restrict__ dinv, int N) {
    int i = blockIdx.x * blockDim.x + threadIdx.x;
    if (i < N) dinv[i] = rsqrtf((float)(deg[i] + 1));  // +1 = self loop
}

// hierarchical exclusive scan: partials -> scan partials -> per-block offsets
__global__ __launch_bounds__(256) void k_part(const int* __restrict__ deg,
                                              int* __restrict__ part, int N) {
    int b = blockIdx.x, t = threadIdx.x;
    int base = b * 1024 + t * 4;
    int s = 0;
    if (base + 3 < N) {
        int4 d = *(const int4*)&deg[base];
        s = d.x + d.y + d.z + d.w;
    } else {
        for (int i = 0; i < 4; i++) if (base + i < N) s += deg[base + i];
    }
    __shared__ int sm[256];
    sm[t] = s; __syncthreads();
    for (int d = 128; d > 0; d >>= 1) { if (t < d) sm[t] += sm[t + d]; __syncthreads(); }
    if (t == 0) part[b] = sm[0];
}

__global__ __launch_bounds__(128) void k_scanpart(const int* __restrict__ part,
                                                  int* __restrict__ poff,
                                                  int* __restrict__ off, int nb, int N) {
    __shared__ int sm[128];
    int t = threadIdx.x;
    sm[t] = (t < nb) ? part[t] : 0;
    __syncthreads();
    for (int d = 1; d < 128; d <<= 1) {
        int v = (t >= d) ? sm[t - d] : 0;
        __syncthreads();
        sm[t] += v;
        __syncthreads();
    }
    poff[t] = (t == 0) ? 0 : sm[t - 1];
    if (t == 127) off[N] = sm[127];
}

__global__ __launch_bounds__(256) void k_off(const int* __restrict__ deg,
                                             const int* __restrict__ poff,
                                             int* __restrict__ off, int N) {
    int b = blockIdx.x, t = threadIdx.x;
    int base = b * 1024 + t * 4;
    int d0 = 0, d1 = 0, d2 = 0, d3 = 0;
    if (base + 3 < N) {
        int4 d = *(const int4*)&deg[base];
        d0 = d.x; d1 = d.y; d2 = d.z; d3 = d.w;
    } else {
        if (base < N) d0 = deg[base];
        if (base + 1 < N) d1 = deg[base + 1];
        if (base + 2 < N) d2 = deg[base + 2];
        if (base + 3 < N) d3 = deg[base + 3];
    }
    int tot = d0 + d1 + d2 + d3;
    __shared__ int sm[256];
    sm[t] = tot; __syncthreads();
    for (int d = 1; d < 256; d <<= 1) {
        int v = (t >= d) ? sm[t - d] : 0;
        __syncthreads();
        sm[t] += v;
        __syncthreads();
    }
    int pre = poff[b] + ((t == 0) ? 0 : sm[t - 1]);
    if (base < N)     off[base] = pre;
    if (base + 1 < N) off[base + 1] = pre + d0;
    if (base + 2 < N) off[base + 2] = pre + d0 + d1;
    if (base + 3 < N) off[base + 3] = pre + d0 + d1 + d2;
}

__global__ void k_fill(const int* __restrict__ row, const int* __restrict__ col,
                       const int* __restrict__ off, int* __restrict__ cur,
                       int* __restrict__ csr, int E) {
    int i = blockIdx.x * blockDim.x + threadIdx.x;
    if (i < E) {
        int c = col[i];
        int p = atomicAdd(&cur[c], 1);
        csr[off[c] + p] = row[i];
    }
}

// ---------- W prep: Wt[n][k] = bf16(W[k][n]) ----------
__global__ void k_prepW(const float* __restrict__ W, unsigned short* __restrict__ Wt) {
    int t = blockIdx.x * blockDim.x + threadIdx.x;  // 16384
    int k = t >> 7, n = t & 127;
    Wt[n * DH + k] = f2b(W[k * DH + n]);
}

// ---------- MFMA GEMM: Y[r][c] = bf16( (X[r]@W)[c] * dinv[r] ) ----------
// 64 rows/block, 256 thr = 4 waves, each wave: 16 rows x 128 cols.
// LDS tiles padded to stride 136 (ushort) for conflict-free ds_read_b128.
__global__ __launch_bounds__(256) void k_gemm_mfma(const void* __restrict__ Xin, int x_is_bf16,
                                                   const unsigned short* __restrict__ Wt,
                                                   const float* __restrict__ dinv,
                                                   unsigned short* __restrict__ Y, int nrows) {
    __shared__ unsigned short Xs[64 * 136];
    __shared__ unsigned short Ws[128 * 136];
    int t = threadIdx.x;
    int row0 = blockIdx.x * 64;

    // stage Wt (bf16, pre-transposed) -> LDS
    for (int v = t; v < 128 * 32; v += 256) {
        int n = v >> 5, kq = v & 31;
        ushort4 w = ((const ushort4*)Wt)[v];
        *(ushort4*)&Ws[n * 136 + kq * 4] = w;
    }
    // stage X tile -> LDS as bf16
    if (x_is_bf16) {
        const unsigned short* X = (const unsigned short*)Xin;
        for (int v = t; v < 64 * 32; v += 256) {
            int r = v >> 5, cq = v & 31;
            int gr = row0 + r;
            ushort4 h;
            if (gr < nrows) h = ((const ushort4*)X)[(size_t)gr * 32 + cq];
            else { h.x = 0; h.y = 0; h.z = 0; h.w = 0; }
            *(ushort4*)&Xs[r * 136 + cq * 4] = h;
        }
    } else {
        const float* X = (const float*)Xin;
        for (int v = t; v < 64 * 32; v += 256) {
            int r = v >> 5, cq = v & 31;
            int gr = row0 + r;
            ushort4 h;
            if (gr < nrows) {
                float4 xv = ((const float4*)X)[(size_t)gr * 32 + cq];
                h.x = f2b(xv.x); h.y = f2b(xv.y); h.z = f2b(xv.z); h.w = f2b(xv.w);
            } else { h.x = 0; h.y = 0; h.z = 0; h.w = 0; }
            *(ushort4*)&Xs[r * 136 + cq * 4] = h;
        }
    }
    __syncthreads();

    int w = t >> 6;          // wave 0..3
    int lane = t & 63;
    int quad = lane >> 4;    // 0..3
    int l16 = lane & 15;
    int rw = w * 16;

    f4_t acc[8];
#pragma unroll
    for (int j = 0; j < 8; j++) acc[j] = (f4_t){0.f, 0.f, 0.f, 0.f};

#pragma unroll
    for (int kk = 0; kk < 4; kk++) {
        int k0 = kk * 32;
        bf8_t a = __builtin_bit_cast(bf8_t,
            *(const short8*)&Xs[(rw + l16) * 136 + k0 + quad * 8]);
#pragma unroll
        for (int j = 0; j < 8; j++) {
            bf8_t b = __builtin_bit_cast(bf8_t,
                *(const short8*)&Ws[(j * 16 + l16) * 136 + k0 + quad * 8]);
            acc[j] = __builtin_amdgcn_mfma_f32_16x16x32_bf16(a, b, acc[j], 0, 0, 0);
        }
    }

    // epilogue: scale by dinv[r], store bf16
#pragma unroll
    for (int reg = 0; reg < 4; reg++) {
        int r = row0 + rw + quad * 4 + reg;
        if (r < nrows) {
            float dv = dinv[r];
#pragma unroll
            for (int j = 0; j < 8; j++) {
                float val = acc[j][reg] * dv;
                Y[(size_t)r * DH + j * 16 + l16] = f2b(val);
            }
        }
    }
}

// ---------- Aggregation (pull, bf16 rows, 4 edge-parallel groups) ----------
// out[n] = act( dinv[n]*(sum_{src} Hs[src] + Hs[n]) + b )
__global__ __launch_bounds__(128) void k_agg(const unsigned short* __restrict__ Hs,
                                             void* __restrict__ Out, int out_bf16,
                                             const float* __restrict__ dinv,
                                             const int* __restrict__ off,
                                             const int* __restrict__ csr,
                                             const float* __restrict__ bias, int elu) {
    int n = blockIdx.x;
    int t = threadIdx.x;
    int g = t >> 5;   // group 0..3
    int l = t & 31;   // lane in group; covers 4 cols each
    int s = off[n], e = off[n + 1];
    const ushort4* rows = (const ushort4*)Hs;  // row r = rows[r*32 + l]

    float a0 = 0.f, a1 = 0.f, a2 = 0.f, a3 = 0.f;
    if (g == 0) {  // self loop
        ushort4 v = rows[(size_t)n * 32 + l];
        a0 += b2f(v.x); a1 += b2f(v.y); a2 += b2f(v.z); a3 += b2f(v.w);
    }
    int i = s + g;
    for (; i + 12 < e; i += 16) {  // 4 independent gather streams per group
        int j0 = csr[i], j1 = csr[i + 4], j2 = csr[i + 8], j3 = csr[i + 12];
        ushort4 v0 = rows[(size_t)j0 * 32 + l];
        ushort4 v1 = rows[(size_t)j1 * 32 + l];
        ushort4 v2 = rows[(size_t)j2 * 32 + l];
        ushort4 v3 = rows[(size_t)j3 * 32 + l];
        a0 += b2f(v0.x) + b2f(v1.x) + b2f(v2.x) + b2f(v3.x);
        a1 += b2f(v0.y) + b2f(v1.y) + b2f(v2.y) + b2f(v3.y);
        a2 += b2f(v0.z) + b2f(v1.z) + b2f(v2.z) + b2f(v3.z);
        a3 += b2f(v0.w) + b2f(v1.w) + b2f(v2.w) + b2f(v3.w);
    }
    for (; i < e; i += 4) {
        int j = csr[i];
        ushort4 v = rows[(size_t)j * 32 + l];
        a0 += b2f(v.x); a1 += b2f(v.y); a2 += b2f(v.z); a3 += b2f(v.w);
    }

    __shared__ float ps[4 * DH];
    ps[g * DH + l * 4 + 0] = a0;
    ps[g * DH + l * 4 + 1] = a1;
    ps[g * DH + l * 4 + 2] = a2;
    ps[g * DH + l * 4 + 3] = a3;
    __syncthreads();

    float v = ps[t] + ps[DH + t] + ps[2 * DH + t] + ps[3 * DH + t];
    v = v * dinv[n] + bias[t];
    if (elu) v = v > 0.f ? v : expm1f(v);
    if (out_bf16) ((unsigned short*)Out)[(size_t)n * DH + t] = f2b(v);
    else          ((float*)Out)[(size_t)n * DH + t] = v;
}

// ---------- Mean pool (batch sorted) ----------
__global__ void k_pool(const float* __restrict__ H, const int* __restrict__ batch,
                       float* __restrict__ Gsum, int* __restrict__ cnts, int N) {
    int g = blockIdx.x;
    int p = blockIdx.y;
    int c = threadIdx.x;  // 128
    int lo = 0, hi = N;
    while (lo < hi) { int m = (lo + hi) >> 1; if (batch[m] < g) lo = m + 1; else hi = m; }
    int s = lo;
    hi = N;
    while (lo < hi) { int m = (lo + hi) >> 1; if (batch[m] < g + 1) lo = m + 1; else hi = m; }
    int e = lo;
    int len = e - s;
    int parts = (int)gridDim.y;
    int chunk = (len + parts - 1) / parts;
    int i0 = s + p * chunk;
    int i1 = min(i0 + chunk, e);
    float acc = 0.f;
    for (int i = i0; i < i1; i++) acc += H[(size_t)i * DH + c];
    atomicAdd(&Gsum[g * DH + c], acc);
    if (p == 0 && c == 0) cnts[g] = len;
}

// ---------- MLP head + log_softmax ----------
__global__ __launch_bounds__(64) void k_head(const float* __restrict__ Gsum,
                                             const int* __restrict__ cnts,
                                             const float* __restrict__ W1,
                                             const float* __restrict__ b1,
                                             const float* __restrict__ W2,
                                             const float* __restrict__ b2,
                                             float* __restrict__ out) {
    int g = blockIdx.x;
    int t = threadIdx.x;
    __shared__ float gv[DH];
    __shared__ float mid[20];
    __shared__ float o[10];
    float inv = 1.f / fmaxf((float)cnts[g], 1.f);
    for (int i = t; i < DH; i += 64) gv[i] = Gsum[g * DH + i] * inv;
    __syncthreads();
    if (t < 20) {
        float a = b1[t];
        for (int k = 0; k < DH; k++) a += gv[k] * W1[k * 20 + t];
        mid[t] = fmaxf(a, 0.f);
    }
    __syncthreads();
    if (t < 10) {
        float a = b2[t];
        for (int k = 0; k < 20; k++) a += mid[k] * W2[k * 10 + t];
        o[t] = a;
    }
    __syncthreads();
    if (t == 0) {
        float m = -1e30f;
        for (int j = 0; j < 10; j++) m = fmaxf(m, o[j]);
        float ssum = 0.f;
        for (int j = 0; j < 10; j++) ssum += expf(o[j] - m);
        float l = logf(ssum);
        for (int j = 0; j < 10; j++) out[g * 10 + j] = o[j] - m - l;
    }
}

extern "C" void kernel_launch(void* const* d_in, const int* in_sizes, int n_in,
                              void* d_out, int out_size, void* d_ws, size_t ws_size,
                              hipStream_t stream) {
    const float* x    = (const float*)d_in[0];
    const int*   ei   = (const int*)d_in[1];
    const int*   batch= (const int*)d_in[2];
    const float* W1   = (const float*)d_in[3];
    const float* b1   = (const float*)d_in[4];
    const float* W2   = (const float*)d_in[5];
    const float* b2   = (const float*)d_in[6];
    const float* fc1W = (const float*)d_in[7];
    const float* fc1b = (const float*)d_in[8];
    const float* fc2W = (const float*)d_in[9];
    const float* fc2b = (const float*)d_in[10];
    float* out = (float*)d_out;

    int N = in_sizes[0] / DH;     // 100000
    int E = in_sizes[1] / 2;      // 1600000
    int G = out_size / 10;        // 64

    char* p = (char*)d_ws;
    auto alloc = [&](size_t bytes) {
        char* r = p;
        p += (bytes + 255) & ~(size_t)255;
        return r;
    };
    // P0: bf16 hidden (hs1 for layer1, reused as hs2 for layer2)
    unsigned short* hs = (unsigned short*)alloc((size_t)N * DH * 2);
    // P1: 51.2MB region: a1 bf16 in first half; a2 fp32 over the whole thing
    char* P1 = (char*)alloc((size_t)N * DH * 4);
    unsigned short* a1 = (unsigned short*)P1;  // bf16, first half
    float* a2 = (float*)P1;                    // fp32, full
    int*   csr  = (int*)alloc((size_t)E * 4);
    int*   deg  = (int*)alloc((size_t)N * 4);
    int*   off  = (int*)alloc((size_t)(N + 1) * 4);
    int*   cur  = (int*)alloc((size_t)N * 4);
    float* dinv = (float*)alloc((size_t)N * 4);
    int*   part = (int*)alloc(1024);
    int*   poff = (int*)alloc(1024);
    unsigned short* Wt1 = (unsigned short*)alloc(DH * DH * 2);
    unsigned short* Wt2 = (unsigned short*)alloc(DH * DH * 2);
    float* Gsum = (float*)alloc((size_t)G * DH * 4);
    int*   cnts = (int*)alloc((size_t)G * 4);

    const int* row = ei;       // message source
    const int* col = ei + E;   // aggregation target

    hipMemsetAsync(deg, 0, (size_t)N * 4, stream);
    hipMemsetAsync(cur, 0, (size_t)N * 4, stream);
    hipMemsetAsync(Gsum, 0, (size_t)G * DH * 4, stream);

    const int tb = 256;
    int nb = (N + 1023) / 1024;  // 98
    k_deg<<<(E + tb - 1) / tb, tb, 0, stream>>>(col, deg, E);
    k_dinv<<<(N + tb - 1) / tb, tb, 0, stream>>>(deg, dinv, N);
    k_part<<<nb, 256, 0, stream>>>(deg, part, N);
    k_scanpart<<<1, 128, 0, stream>>>(part, poff, off, nb, N);
    k_off<<<nb, 256, 0, stream>>>(deg, poff, off, N);
    k_fill<<<(E + tb - 1) / tb, tb, 0, stream>>>(row, col, off, cur, csr, E);

    k_prepW<<<64, 256, 0, stream>>>(W1, Wt1);
    k_prepW<<<64, 256, 0, stream>>>(W2, Wt2);

    int gblocks = (N + 63) / 64;
    // layer 1
    k_gemm_mfma<<<gblocks, 256, 0, stream>>>(x, 0, Wt1, dinv, hs, N);
    k_agg<<<N, 128, 0, stream>>>(hs, a1, 1, dinv, off, csr, b1, 1);
    // layer 2
    k_gemm_mfma<<<gblocks, 256, 0, stream>>>(a1, 1, Wt2, dinv, hs, N);
    k_agg<<<N, 128, 0, stream>>>(hs, a2, 0, dinv, off, csr, b2, 0);

    dim3 pg(G, 8);
    k_pool<<<pg, DH, 0, stream>>>(a2, batch, Gsum, cnts, N);
    k_head<<<G, 64, 0, stream>>>(Gsum, cnts, fc1W, fc1b, fc2W, fc2b, out);
}